// Round 8
// baseline (98.101 us; speedup 1.0000x reference)
//
#include <hip/hip_runtime.h>
#include <hip/hip_fp16.h>

#define SPATIAL_SCALE 0.0625f
#define P_OUT 7
#define OUTPUT_DIM 256
#define PART_SIZE 7
#define SAMPLE_PER_PART 4
#define TRANS_STD 0.1f

#define NROIS 128
#define NBINS (P_OUT * P_OUT)            // 49
#define NWAVES (NROIS * NBINS)           // 6272
#define GBLOCKS (NWAVES / 4)             // 1568 = 8 * 196
#define TPBLOCKS 2048                    // 128 sx * 8 ct * 2 b

// ---------------------------------------------------------------------------
// Kernel 1: transpose data [B=2][C=256][S=16384] -> dataT f16 [B][S][C].
// 32 channels x 128 spatial per block; float4 loads, 8 B f16 stores.
// ---------------------------------------------------------------------------
#define TP_SP 133   // padded LDS row stride; 133 mod 32 = 5
__global__ __launch_bounds__(256) void transpose_kernel(
    const float* __restrict__ in,
    __half* __restrict__ dataT)
{
    __shared__ float tile[32 * TP_SP];
    const int bid = blockIdx.x;
    const int st = (bid & 127) * 128;        // spatial tile base
    const int ct = ((bid >> 7) & 7) * 32;    // channel tile base
    const int b  = bid >> 10;
    const int tid = threadIdx.x;

    const float* inb  = in    + (size_t)b * 256 * 16384;
    __half*      outb = dataT + (size_t)b * 16384 * 256;

    {
        const int sx = (tid & 31) * 4;
        const int cy = tid >> 5;
        #pragma unroll
        for (int k = 0; k < 4; ++k) {
            const int c_local = cy + 8 * k;
            const float4 v = *(const float4*)(inb + (size_t)(ct + c_local) * 16384 + st + sx);
            float* tt = &tile[c_local * TP_SP + sx];
            tt[0] = v.x; tt[1] = v.y; tt[2] = v.z; tt[3] = v.w;
        }
    }
    __syncthreads();
    {
        const int cq = (tid & 7) * 4;
        const int sl = tid >> 3;
        #pragma unroll
        for (int k = 0; k < 4; ++k) {
            const int s_local = sl + 32 * k;
            __half2 h0 = __floats2half2_rn(tile[(cq + 0) * TP_SP + s_local],
                                           tile[(cq + 1) * TP_SP + s_local]);
            __half2 h1 = __floats2half2_rn(tile[(cq + 2) * TP_SP + s_local],
                                           tile[(cq + 3) * TP_SP + s_local]);
            uint2 uu;
            uu.x = *reinterpret_cast<unsigned*>(&h0);
            uu.y = *reinterpret_cast<unsigned*>(&h1);
            *reinterpret_cast<uint2*>(outb + (size_t)(st + s_local) * 256 + ct + cq) = uu;
        }
    }
}

// ---------------------------------------------------------------------------
// Kernel 2: gather with INLINE per-bin separable weights + fused remap.
// One wave per (n,bin); lane = 8 channels (16 B f16); half-waves = even/odd
// window x-pixels. Block = 4 consecutive bins; LDS merge; out[n][c][bin].
// Weight construction uses static-index select-sums (no scratch).
// ---------------------------------------------------------------------------
__global__ __launch_bounds__(256) void gather_kernel(
    const __half* __restrict__ dataT,   // [B][H*W][C] f16
    const float* __restrict__ rois,
    const float* __restrict__ offset,
    float* __restrict__ outp)           // [n][c][bin]
{
    __shared__ float lds[4 * 2 * 256];

    const int bid  = blockIdx.x;
    const int bswz = (bid & 7) * (GBLOCKS / 8) + (bid >> 3);   // bijective XCD swizzle
    const int w    = threadIdx.x >> 6;
    const int lane = threadIdx.x & 63;
    const int l    = bswz * 4 + w;          // wave id = (n, bin)

    const int n   = l / NBINS;
    const int bin = l - n * NBINS;
    const int pw  = bin % P_OUT;
    const int ph  = bin / P_OUT;

    // ---- roi math (wave-uniform) ----
    const float* roi = rois + n * 5;
    const int   b   = (int)roi[0];
    const float rsw = rintf(roi[1]) * SPATIAL_SCALE - 0.5f;
    const float rsh = rintf(roi[2]) * SPATIAL_SCALE - 0.5f;
    const float rew = (rintf(roi[3]) + 1.0f) * SPATIAL_SCALE - 0.5f;
    const float reh = (rintf(roi[4]) + 1.0f) * SPATIAL_SCALE - 0.5f;
    const float rw  = fmaxf(rew - rsw, 0.1f);
    const float rh  = fmaxf(reh - rsh, 0.1f);
    const float binw = rw * (1.0f / P_OUT);
    const float binh = rh * (1.0f / P_OUT);
    const float subw = binw * (1.0f / SAMPLE_PER_PART);
    const float subh = binh * (1.0f / SAMPLE_PER_PART);

    // part_h == ph, part_w == pw (P == PART_SIZE == 7, fp32-exact)
    const float tx = offset[(n * 2 + 0) * (PART_SIZE * PART_SIZE) + ph * PART_SIZE + pw] * TRANS_STD;
    const float ty = offset[(n * 2 + 1) * (PART_SIZE * PART_SIZE) + ph * PART_SIZE + pw] * TRANS_STD;

    const float wstart = (float)pw * binw + rsw + tx * rw;
    const float hstart = (float)ph * binh + rsh + ty * rh;

    // ---- inline separable weights, static indexing only ----
    // x axis
    int   fxi[SAMPLE_PER_PART]; float dxa[SAMPLE_PER_PART], va[SAMPLE_PER_PART];
    const int Fx = (int)floorf(fminf(fmaxf(wstart, 0.0f), 127.0f));
    float cX = 0.0f;
    #pragma unroll
    for (int j = 0; j < SAMPLE_PER_PART; ++j) {
        const float wv = wstart + (float)j * subw;
        const float wc = fminf(fmaxf(wv, 0.0f), 127.0f);
        const float ff = floorf(wc);
        fxi[j] = (int)ff;
        dxa[j] = wc - ff;
        va[j]  = ((wv >= -0.5f) && (wv <= 127.5f)) ? 1.0f : 0.0f;
        cX += va[j];
    }
    const float wcL = fminf(fmaxf(wstart + 3.0f * subw, 0.0f), 127.0f);
    const int nx = min((int)ceilf(wcL) - Fx + 1, 8);
    const float sX = 1.0f / fmaxf(cX, 1.0f);
    float wx[8];
    #pragma unroll
    for (int k = 0; k < 8; ++k) {
        float a = 0.0f;
        #pragma unroll
        for (int j = 0; j < SAMPLE_PER_PART; ++j) {
            const int ci = fxi[j] + ((dxa[j] > 0.0f) ? 1 : 0);   // ceil
            a += (fxi[j] - Fx == k) ? va[j] * (1.0f - dxa[j]) : 0.0f;
            a += (ci     - Fx == k) ? va[j] * dxa[j]          : 0.0f;
        }
        wx[k] = a * sX;
    }
    // y axis
    int   fyi[SAMPLE_PER_PART]; float dya[SAMPLE_PER_PART], vb[SAMPLE_PER_PART];
    const int Fy = (int)floorf(fminf(fmaxf(hstart, 0.0f), 127.0f));
    float cY = 0.0f;
    #pragma unroll
    for (int j = 0; j < SAMPLE_PER_PART; ++j) {
        const float hv = hstart + (float)j * subh;
        const float hc = fminf(fmaxf(hv, 0.0f), 127.0f);
        const float ff = floorf(hc);
        fyi[j] = (int)ff;
        dya[j] = hc - ff;
        vb[j]  = ((hv >= -0.5f) && (hv <= 127.5f)) ? 1.0f : 0.0f;
        cY += vb[j];
    }
    const float hcL = fminf(fmaxf(hstart + 3.0f * subh, 0.0f), 127.0f);
    const int ny = min((int)ceilf(hcL) - Fy + 1, 8);
    const float sY = 1.0f / fmaxf(cY, 1.0f);
    float wy[8];
    #pragma unroll
    for (int k = 0; k < 8; ++k) {
        float a = 0.0f;
        #pragma unroll
        for (int j = 0; j < SAMPLE_PER_PART; ++j) {
            const int ci = fyi[j] + ((dya[j] > 0.0f) ? 1 : 0);
            a += (fyi[j] - Fy == k) ? vb[j] * (1.0f - dya[j]) : 0.0f;
            a += (ci     - Fy == k) ? vb[j] * dya[j]          : 0.0f;
        }
        wy[k] = a * sY;
    }

    // ---- windowed gather ----
    const int half_id = lane >> 5;           // 0: even x-pixels, 1: odd
    const int c0      = (lane & 31) * 8;     // 8 channels per lane

    float mwx[4];
    if (half_id) { mwx[0] = wx[1]; mwx[1] = wx[3]; mwx[2] = wx[5]; mwx[3] = wx[7]; }
    else         { mwx[0] = wx[0]; mwx[1] = wx[2]; mwx[2] = wx[4]; mwx[3] = wx[6]; }

    const __half* base = dataT
        + ((size_t)b * (128 * 128) + (size_t)Fy * 128 + Fx) * 256 + c0;

    float acc[8] = {0,0,0,0,0,0,0,0};

    #pragma unroll
    for (int ky = 0; ky < 8; ++ky) {
        if (ky >= ny) break;                                // wave-uniform
        const float wyk = wy[ky];                            // static index
        const __half* rowp = base + (size_t)ky * (128 * 256);
        #pragma unroll
        for (int kp = 0; kp < 4; ++kp) {
            if (2 * kp >= nx) break;                        // wave-uniform
            const int pxr = 2 * kp + half_id;
            const int px  = min(pxr, nx - 1);               // clamp addr; weight 0 there
            const float wgt = wyk * mwx[kp];
            const uint4 u = *(const uint4*)(rowp + (size_t)px * 256);
            {
                __half2 h = *reinterpret_cast<const __half2*>(&u.x);
                float2 f = __half22float2(h);
                acc[0] += wgt * f.x; acc[1] += wgt * f.y;
            }
            {
                __half2 h = *reinterpret_cast<const __half2*>(&u.y);
                float2 f = __half22float2(h);
                acc[2] += wgt * f.x; acc[3] += wgt * f.y;
            }
            {
                __half2 h = *reinterpret_cast<const __half2*>(&u.z);
                float2 f = __half22float2(h);
                acc[4] += wgt * f.x; acc[5] += wgt * f.y;
            }
            {
                __half2 h = *reinterpret_cast<const __half2*>(&u.w);
                float2 f = __half22float2(h);
                acc[6] += wgt * f.x; acc[7] += wgt * f.y;
            }
        }
    }

    // stage partials: lds[w][half][c]
    float* myl = &lds[(w * 2 + half_id) * 256 + c0];
    #pragma unroll
    for (int k = 0; k < 8; ++k) myl[k] = acc[k];
    __syncthreads();

    // output: thread t owns channel c=t for the block's 4 bins
    const int c  = threadIdx.x;
    const int l0 = bswz * 4;
    #pragma unroll
    for (int j = 0; j < 4; ++j) {
        const int lj  = l0 + j;
        const int nn  = lj / NBINS;
        const int bb  = lj - nn * NBINS;
        const float v = lds[(j * 2 + 0) * 256 + c] + lds[(j * 2 + 1) * 256 + c];
        outp[(size_t)nn * (OUTPUT_DIM * NBINS) + (size_t)c * NBINS + bb] = v;
    }
}

// ---------------------------------------------------------------------------
// Fallback (round-0): direct gather from NCHW layout, used if ws too small.
// ---------------------------------------------------------------------------
__global__ __launch_bounds__(256) void dpsroi_kernel_direct(
    const float* __restrict__ data,
    const float* __restrict__ rois,
    const float* __restrict__ offset,
    float* __restrict__ out,
    int total)
{
    int idx = blockIdx.x * blockDim.x + threadIdx.x;
    if (idx >= total) return;

    const int P = P_OUT;
    const int C = OUTPUT_DIM;
    const int H = 128, W = 128;

    int pw = idx % P;
    int ph = (idx / P) % P;
    int c  = (idx / (P * P)) % C;
    int n  = idx / (P * P * C);

    const float* roi = rois + n * 5;
    int   b   = (int)roi[0];
    float rsw = rintf(roi[1]) * SPATIAL_SCALE - 0.5f;
    float rsh = rintf(roi[2]) * SPATIAL_SCALE - 0.5f;
    float rew = (rintf(roi[3]) + 1.0f) * SPATIAL_SCALE - 0.5f;
    float reh = (rintf(roi[4]) + 1.0f) * SPATIAL_SCALE - 0.5f;
    float rw  = fmaxf(rew - rsw, 0.1f);
    float rh  = fmaxf(reh - rsh, 0.1f);
    float binw = rw / P, binh = rh / P;
    float subw = binw / SAMPLE_PER_PART, subh = binh / SAMPLE_PER_PART;

    float tx = offset[(n * 2 + 0) * (PART_SIZE * PART_SIZE) + ph * PART_SIZE + pw] * TRANS_STD;
    float ty = offset[(n * 2 + 1) * (PART_SIZE * PART_SIZE) + ph * PART_SIZE + pw] * TRANS_STD;

    float wstart = (float)pw * binw + rsw + tx * rw;
    float hstart = (float)ph * binh + rsh + ty * rh;

    const float* dplane = data + (size_t)(b * C + c) * (H * W);

    float ssum = 0.0f, count = 0.0f;
    #pragma unroll
    for (int ihs = 0; ihs < SAMPLE_PER_PART; ++ihs) {
        float hh = hstart + (float)ihs * subh;
        #pragma unroll
        for (int iws = 0; iws < SAMPLE_PER_PART; ++iws) {
            float ww = wstart + (float)iws * subw;
            float valid = ((ww >= -0.5f) & (ww <= (float)W - 0.5f) &
                           (hh >= -0.5f) & (hh <= (float)H - 0.5f)) ? 1.0f : 0.0f;
            float wc = fminf(fmaxf(ww, 0.0f), (float)W - 1.0f);
            float hc = fminf(fmaxf(hh, 0.0f), (float)H - 1.0f);
            float y0f = floorf(hc), x0f = floorf(wc);
            float y1f = ceilf(hc),  x1f = ceilf(wc);
            float dy = hc - y0f, dx = wc - x0f;
            int y0 = (int)y0f, y1 = (int)y1f;
            int x0 = (int)x0f, x1 = (int)x1f;
            float v00 = dplane[y0 * W + x0];
            float v01 = dplane[y0 * W + x1];
            float v10 = dplane[y1 * W + x0];
            float v11 = dplane[y1 * W + x1];
            float val = (1.0f - dy) * (1.0f - dx) * v00
                      + (1.0f - dy) * dx          * v01
                      + dy          * (1.0f - dx) * v10
                      + dy          * dx          * v11;
            ssum  += val * valid;
            count += valid;
        }
    }
    out[idx] = (count > 0.0f) ? (ssum / fmaxf(count, 1.0f)) : 0.0f;
}

extern "C" void kernel_launch(void* const* d_in, const int* in_sizes, int n_in,
                              void* d_out, int out_size, void* d_ws, size_t ws_size,
                              hipStream_t stream) {
    const float* data   = (const float*)d_in[0];
    const float* rois   = (const float*)d_in[1];
    const float* offset = (const float*)d_in[2];
    float* out = (float*)d_out;

    const size_t szT = (size_t)2 * 16384 * 256 * sizeof(__half);   // 16.78 MB

    if (ws_size >= szT) {
        __half* dataT = (__half*)d_ws;
        transpose_kernel<<<TPBLOCKS, 256, 0, stream>>>(data, dataT);
        gather_kernel<<<GBLOCKS, 256, 0, stream>>>(dataT, rois, offset, out);
    } else {
        int total = out_size;
        dpsroi_kernel_direct<<<(total + 255) / 256, 256, 0, stream>>>(data, rois, offset, out, total);
    }
}

// Round 12
// 96.515 us; speedup vs baseline: 1.0164x; 1.0164x over previous
//
#include <hip/hip_runtime.h>
#include <hip/hip_fp16.h>

#define SPATIAL_SCALE 0.0625f
#define P_OUT 7
#define OUTPUT_DIM 256
#define PART_SIZE 7
#define SAMPLE_PER_PART 4
#define TRANS_STD 0.1f

#define NROIS 128
#define NBINS (P_OUT * P_OUT)            // 49
#define GROUPS 13                        // 4-aligned bin groups per roi (12x4 + 1)
#define GBLOCKS (NROIS * GROUPS)         // 1664 = 8 * 208
#define TPBLOCKS 2048                    // 128 sx * 8 ct * 2 b

// ---------------------------------------------------------------------------
// Kernel 1: transpose data [B=2][C=256][S=16384] -> dataT f16 [B][S][C].
// 32 channels x 128 spatial per block; float4 loads, 8 B f16 stores.
// ---------------------------------------------------------------------------
#define TP_SP 133   // padded LDS row stride; 133 mod 32 = 5
__global__ __launch_bounds__(256) void transpose_kernel(
    const float* __restrict__ in,
    __half* __restrict__ dataT)
{
    __shared__ float tile[32 * TP_SP];
    const int bid = blockIdx.x;
    const int st = (bid & 127) * 128;        // spatial tile base
    const int ct = ((bid >> 7) & 7) * 32;    // channel tile base
    const int b  = bid >> 10;
    const int tid = threadIdx.x;

    const float* inb  = in    + (size_t)b * 256 * 16384;
    __half*      outb = dataT + (size_t)b * 16384 * 256;

    {
        const int sx = (tid & 31) * 4;
        const int cy = tid >> 5;
        #pragma unroll
        for (int k = 0; k < 4; ++k) {
            const int c_local = cy + 8 * k;
            const float4 v = *(const float4*)(inb + (size_t)(ct + c_local) * 16384 + st + sx);
            float* tt = &tile[c_local * TP_SP + sx];
            tt[0] = v.x; tt[1] = v.y; tt[2] = v.z; tt[3] = v.w;
        }
    }
    __syncthreads();
    {
        const int cq = (tid & 7) * 4;
        const int sl = tid >> 3;
        #pragma unroll
        for (int k = 0; k < 4; ++k) {
            const int s_local = sl + 32 * k;
            __half2 h0 = __floats2half2_rn(tile[(cq + 0) * TP_SP + s_local],
                                           tile[(cq + 1) * TP_SP + s_local]);
            __half2 h1 = __floats2half2_rn(tile[(cq + 2) * TP_SP + s_local],
                                           tile[(cq + 3) * TP_SP + s_local]);
            uint2 uu;
            uu.x = *reinterpret_cast<unsigned*>(&h0);
            uu.y = *reinterpret_cast<unsigned*>(&h1);
            *reinterpret_cast<uint2*>(outb + (size_t)(st + s_local) * 256 + ct + cq) = uu;
        }
    }
}

// ---------------------------------------------------------------------------
// Kernel 2: gather with inline separable weights + coalesced-run stores.
// Block = one 4-aligned bin group of one roi (wave w -> bin g*4+w).
// Store remap: thread -> (c = idx>>2, j = idx&3) so lanes write 4-bin
// contiguous runs; HW coalescer merges same-line lanes (~3x fewer line ops).
// ---------------------------------------------------------------------------
__global__ __launch_bounds__(256) void gather_kernel(
    const __half* __restrict__ dataT,   // [B][H*W][C] f16
    const float* __restrict__ rois,
    const float* __restrict__ offset,
    float* __restrict__ outp)           // [n][c][bin]
{
    __shared__ float lds[4 * 2 * 256];

    const int bid  = blockIdx.x;
    const int bswz = (bid & 7) * (GBLOCKS / 8) + (bid >> 3);   // bijective XCD swizzle
    const int w    = threadIdx.x >> 6;
    const int lane = threadIdx.x & 63;

    const int n   = bswz / GROUPS;
    const int g   = bswz - n * GROUPS;
    const int bin = g * 4 + w;               // >= 49 possible only when g == 12, w > 0

    if (bin < NBINS) {
        const int pw  = bin % P_OUT;
        const int ph  = bin / P_OUT;

        // ---- roi math (wave-uniform) ----
        const float* roi = rois + n * 5;
        const int   b   = (int)roi[0];
        const float rsw = rintf(roi[1]) * SPATIAL_SCALE - 0.5f;
        const float rsh = rintf(roi[2]) * SPATIAL_SCALE - 0.5f;
        const float rew = (rintf(roi[3]) + 1.0f) * SPATIAL_SCALE - 0.5f;
        const float reh = (rintf(roi[4]) + 1.0f) * SPATIAL_SCALE - 0.5f;
        const float rw  = fmaxf(rew - rsw, 0.1f);
        const float rh  = fmaxf(reh - rsh, 0.1f);
        const float binw = rw * (1.0f / P_OUT);
        const float binh = rh * (1.0f / P_OUT);
        const float subw = binw * (1.0f / SAMPLE_PER_PART);
        const float subh = binh * (1.0f / SAMPLE_PER_PART);

        // part_h == ph, part_w == pw (P == PART_SIZE == 7, fp32-exact)
        const float tx = offset[(n * 2 + 0) * (PART_SIZE * PART_SIZE) + ph * PART_SIZE + pw] * TRANS_STD;
        const float ty = offset[(n * 2 + 1) * (PART_SIZE * PART_SIZE) + ph * PART_SIZE + pw] * TRANS_STD;

        const float wstart = (float)pw * binw + rsw + tx * rw;
        const float hstart = (float)ph * binh + rsh + ty * rh;

        // ---- inline separable weights, static indexing only ----
        int   fxi[SAMPLE_PER_PART]; float dxa[SAMPLE_PER_PART], va[SAMPLE_PER_PART];
        const int Fx = (int)floorf(fminf(fmaxf(wstart, 0.0f), 127.0f));
        float cX = 0.0f;
        #pragma unroll
        for (int j = 0; j < SAMPLE_PER_PART; ++j) {
            const float wv = wstart + (float)j * subw;
            const float wc = fminf(fmaxf(wv, 0.0f), 127.0f);
            const float ff = floorf(wc);
            fxi[j] = (int)ff;
            dxa[j] = wc - ff;
            va[j]  = ((wv >= -0.5f) && (wv <= 127.5f)) ? 1.0f : 0.0f;
            cX += va[j];
        }
        const float wcL = fminf(fmaxf(wstart + 3.0f * subw, 0.0f), 127.0f);
        const int nx = min((int)ceilf(wcL) - Fx + 1, 8);
        const float sX = 1.0f / fmaxf(cX, 1.0f);
        float wx[8];
        #pragma unroll
        for (int k = 0; k < 8; ++k) {
            float a = 0.0f;
            #pragma unroll
            for (int j = 0; j < SAMPLE_PER_PART; ++j) {
                const int ci = fxi[j] + ((dxa[j] > 0.0f) ? 1 : 0);   // ceil
                a += (fxi[j] - Fx == k) ? va[j] * (1.0f - dxa[j]) : 0.0f;
                a += (ci     - Fx == k) ? va[j] * dxa[j]          : 0.0f;
            }
            wx[k] = a * sX;
        }
        int   fyi[SAMPLE_PER_PART]; float dya[SAMPLE_PER_PART], vb[SAMPLE_PER_PART];
        const int Fy = (int)floorf(fminf(fmaxf(hstart, 0.0f), 127.0f));
        float cY = 0.0f;
        #pragma unroll
        for (int j = 0; j < SAMPLE_PER_PART; ++j) {
            const float hv = hstart + (float)j * subh;
            const float hc = fminf(fmaxf(hv, 0.0f), 127.0f);
            const float ff = floorf(hc);
            fyi[j] = (int)ff;
            dya[j] = hc - ff;
            vb[j]  = ((hv >= -0.5f) && (hv <= 127.5f)) ? 1.0f : 0.0f;
            cY += vb[j];
        }
        const float hcL = fminf(fmaxf(hstart + 3.0f * subh, 0.0f), 127.0f);
        const int ny = min((int)ceilf(hcL) - Fy + 1, 8);
        const float sY = 1.0f / fmaxf(cY, 1.0f);
        float wy[8];
        #pragma unroll
        for (int k = 0; k < 8; ++k) {
            float a = 0.0f;
            #pragma unroll
            for (int j = 0; j < SAMPLE_PER_PART; ++j) {
                const int ci = fyi[j] + ((dya[j] > 0.0f) ? 1 : 0);
                a += (fyi[j] - Fy == k) ? vb[j] * (1.0f - dya[j]) : 0.0f;
                a += (ci     - Fy == k) ? vb[j] * dya[j]          : 0.0f;
            }
            wy[k] = a * sY;
        }

        // ---- windowed gather ----
        const int half_id = lane >> 5;           // 0: even x-pixels, 1: odd
        const int c0      = (lane & 31) * 8;     // 8 channels per lane

        float mwx[4];
        if (half_id) { mwx[0] = wx[1]; mwx[1] = wx[3]; mwx[2] = wx[5]; mwx[3] = wx[7]; }
        else         { mwx[0] = wx[0]; mwx[1] = wx[2]; mwx[2] = wx[4]; mwx[3] = wx[6]; }

        const __half* base = dataT
            + ((size_t)b * (128 * 128) + (size_t)Fy * 128 + Fx) * 256 + c0;

        float acc[8] = {0,0,0,0,0,0,0,0};

        #pragma unroll
        for (int ky = 0; ky < 8; ++ky) {
            if (ky >= ny) break;                                // wave-uniform
            const float wyk = wy[ky];                            // static index
            const __half* rowp = base + (size_t)ky * (128 * 256);
            #pragma unroll
            for (int kp = 0; kp < 4; ++kp) {
                if (2 * kp >= nx) break;                        // wave-uniform
                const int pxr = 2 * kp + half_id;
                const int px  = min(pxr, nx - 1);               // clamp addr; weight 0 there
                const float wgt = wyk * mwx[kp];
                const uint4 u = *(const uint4*)(rowp + (size_t)px * 256);
                {
                    __half2 h = *reinterpret_cast<const __half2*>(&u.x);
                    float2 f = __half22float2(h);
                    acc[0] += wgt * f.x; acc[1] += wgt * f.y;
                }
                {
                    __half2 h = *reinterpret_cast<const __half2*>(&u.y);
                    float2 f = __half22float2(h);
                    acc[2] += wgt * f.x; acc[3] += wgt * f.y;
                }
                {
                    __half2 h = *reinterpret_cast<const __half2*>(&u.z);
                    float2 f = __half22float2(h);
                    acc[4] += wgt * f.x; acc[5] += wgt * f.y;
                }
                {
                    __half2 h = *reinterpret_cast<const __half2*>(&u.w);
                    float2 f = __half22float2(h);
                    acc[6] += wgt * f.x; acc[7] += wgt * f.y;
                }
            }
        }

        // stage partials: lds[w][half][c]
        float* myl = &lds[(w * 2 + half_id) * 256 + c0];
        #pragma unroll
        for (int k = 0; k < 8; ++k) myl[k] = acc[k];
    }
    __syncthreads();

    // coalesced-run store: idx -> (c = idx>>2, j = idx&3); 4-bin runs per c.
    const int t = threadIdx.x;
    const size_t obase = (size_t)n * (OUTPUT_DIM * NBINS) + g * 4;
    #pragma unroll
    for (int it = 0; it < 4; ++it) {
        const int idx = it * 256 + t;
        const int c = idx >> 2;
        const int j = idx & 3;
        if (g * 4 + j < NBINS) {
            const float v = lds[(j * 2 + 0) * 256 + c] + lds[(j * 2 + 1) * 256 + c];
            outp[obase + (size_t)c * NBINS + j] = v;
        }
    }
}

// ---------------------------------------------------------------------------
// Fallback (round-0): direct gather from NCHW layout, used if ws too small.
// ---------------------------------------------------------------------------
__global__ __launch_bounds__(256) void dpsroi_kernel_direct(
    const float* __restrict__ data,
    const float* __restrict__ rois,
    const float* __restrict__ offset,
    float* __restrict__ out,
    int total)
{
    int idx = blockIdx.x * blockDim.x + threadIdx.x;
    if (idx >= total) return;

    const int P = P_OUT;
    const int C = OUTPUT_DIM;
    const int H = 128, W = 128;

    int pw = idx % P;
    int ph = (idx / P) % P;
    int c  = (idx / (P * P)) % C;
    int n  = idx / (P * P * C);

    const float* roi = rois + n * 5;
    int   b   = (int)roi[0];
    float rsw = rintf(roi[1]) * SPATIAL_SCALE - 0.5f;
    float rsh = rintf(roi[2]) * SPATIAL_SCALE - 0.5f;
    float rew = (rintf(roi[3]) + 1.0f) * SPATIAL_SCALE - 0.5f;
    float reh = (rintf(roi[4]) + 1.0f) * SPATIAL_SCALE - 0.5f;
    float rw  = fmaxf(rew - rsw, 0.1f);
    float rh  = fmaxf(reh - rsh, 0.1f);
    float binw = rw / P, binh = rh / P;
    float subw = binw / SAMPLE_PER_PART, subh = binh / SAMPLE_PER_PART;

    float tx = offset[(n * 2 + 0) * (PART_SIZE * PART_SIZE) + ph * PART_SIZE + pw] * TRANS_STD;
    float ty = offset[(n * 2 + 1) * (PART_SIZE * PART_SIZE) + ph * PART_SIZE + pw] * TRANS_STD;

    float wstart = (float)pw * binw + rsw + tx * rw;
    float hstart = (float)ph * binh + rsh + ty * rh;

    const float* dplane = data + (size_t)(b * C + c) * (H * W);

    float ssum = 0.0f, count = 0.0f;
    #pragma unroll
    for (int ihs = 0; ihs < SAMPLE_PER_PART; ++ihs) {
        float hh = hstart + (float)ihs * subh;
        #pragma unroll
        for (int iws = 0; iws < SAMPLE_PER_PART; ++iws) {
            float ww = wstart + (float)iws * subw;
            float valid = ((ww >= -0.5f) & (ww <= (float)W - 0.5f) &
                           (hh >= -0.5f) & (hh <= (float)H - 0.5f)) ? 1.0f : 0.0f;
            float wc = fminf(fmaxf(ww, 0.0f), (float)W - 1.0f);
            float hc = fminf(fmaxf(hh, 0.0f), (float)H - 1.0f);
            float y0f = floorf(hc), x0f = floorf(wc);
            float y1f = ceilf(hc),  x1f = ceilf(wc);
            float dy = hc - y0f, dx = wc - x0f;
            int y0 = (int)y0f, y1 = (int)y1f;
            int x0 = (int)x0f, x1 = (int)x1f;
            float v00 = dplane[y0 * W + x0];
            float v01 = dplane[y0 * W + x1];
            float v10 = dplane[y1 * W + x0];
            float v11 = dplane[y1 * W + x1];
            float val = (1.0f - dy) * (1.0f - dx) * v00
                      + (1.0f - dy) * dx          * v01
                      + dy          * (1.0f - dx) * v10
                      + dy          * dx          * v11;
            ssum  += val * valid;
            count += valid;
        }
    }
    out[idx] = (count > 0.0f) ? (ssum / fmaxf(count, 1.0f)) : 0.0f;
}

extern "C" void kernel_launch(void* const* d_in, const int* in_sizes, int n_in,
                              void* d_out, int out_size, void* d_ws, size_t ws_size,
                              hipStream_t stream) {
    const float* data   = (const float*)d_in[0];
    const float* rois   = (const float*)d_in[1];
    const float* offset = (const float*)d_in[2];
    float* out = (float*)d_out;

    const size_t szT = (size_t)2 * 16384 * 256 * sizeof(__half);   // 16.78 MB

    if (ws_size >= szT) {
        __half* dataT = (__half*)d_ws;
        transpose_kernel<<<TPBLOCKS, 256, 0, stream>>>(data, dataT);
        gather_kernel<<<GBLOCKS, 256, 0, stream>>>(dataT, rois, offset, out);
    } else {
        int total = out_size;
        dpsroi_kernel_direct<<<(total + 255) / 256, 256, 0, stream>>>(data, rois, offset, out, total);
    }
}

// Round 14
// 91.497 us; speedup vs baseline: 1.0722x; 1.0548x over previous
//
#include <hip/hip_runtime.h>
#include <hip/hip_fp16.h>

#define SPATIAL_SCALE 0.0625f
#define P_OUT 7
#define OUTPUT_DIM 256
#define PART_SIZE 7
#define SAMPLE_PER_PART 4
#define TRANS_STD 0.1f

#define NROIS 128
#define NBINS (P_OUT * P_OUT)            // 49
#define NWAVES (NROIS * NBINS)           // 6272
#define GROUPS 13                        // 4-aligned bin groups per roi
#define GBLOCKS (NROIS * GROUPS)         // 1664 = 8 * 208
#define TPBLOCKS 2048                    // 128 sx * 8 ct * 2 b
#define PRMBLOCKS ((NWAVES + 255) / 256) // 25

// Per-bin separable-weight parameters (96 B). wx/wy zero outside window,
// pre-scaled by 1/max(count,1) per axis.
struct BinParam {
    float wx[8];
    float wy[8];
    int   fx, fy;    // window origin (in-bounds)
    int   nx, ny;    // window extent (<= 8)
    int   b;
    int   pad[3];
};

// ---------------------------------------------------------------------------
// Kernel 1 (fused): blocks [0,2048) transpose data [B][C][S] -> dataT f16
// [B][S][C]; blocks [2048,2073) compute per-bin separable weights.
// ---------------------------------------------------------------------------
#define TP_SP 133   // padded LDS row stride; 133 mod 32 = 5
__global__ __launch_bounds__(256) void prep_kernel(
    const float* __restrict__ in,
    const float* __restrict__ rois,
    const float* __restrict__ offset,
    __half* __restrict__ dataT,
    BinParam* __restrict__ prm)
{
    __shared__ float tile[32 * TP_SP];
    const int bid = blockIdx.x;

    if (bid < TPBLOCKS) {
        const int st = (bid & 127) * 128;        // spatial tile base
        const int ct = ((bid >> 7) & 7) * 32;    // channel tile base
        const int b  = bid >> 10;
        const int tid = threadIdx.x;

        const float* inb  = in    + (size_t)b * 256 * 16384;
        __half*      outb = dataT + (size_t)b * 16384 * 256;

        {
            const int sx = (tid & 31) * 4;
            const int cy = tid >> 5;
            #pragma unroll
            for (int k = 0; k < 4; ++k) {
                const int c_local = cy + 8 * k;
                const float4 v = *(const float4*)(inb + (size_t)(ct + c_local) * 16384 + st + sx);
                float* tt = &tile[c_local * TP_SP + sx];
                tt[0] = v.x; tt[1] = v.y; tt[2] = v.z; tt[3] = v.w;
            }
        }
        __syncthreads();
        {
            const int cq = (tid & 7) * 4;
            const int sl = tid >> 3;
            #pragma unroll
            for (int k = 0; k < 4; ++k) {
                const int s_local = sl + 32 * k;
                __half2 h0 = __floats2half2_rn(tile[(cq + 0) * TP_SP + s_local],
                                               tile[(cq + 1) * TP_SP + s_local]);
                __half2 h1 = __floats2half2_rn(tile[(cq + 2) * TP_SP + s_local],
                                               tile[(cq + 3) * TP_SP + s_local]);
                uint2 uu;
                uu.x = *reinterpret_cast<unsigned*>(&h0);
                uu.y = *reinterpret_cast<unsigned*>(&h1);
                *reinterpret_cast<uint2*>(outb + (size_t)(st + s_local) * 256 + ct + cq) = uu;
            }
        }
        return;
    }

    // ---- params: one thread per (n, bin) ----
    const int t = (bid - TPBLOCKS) * 256 + threadIdx.x;
    if (t >= NWAVES) return;
    const int bin = t % NBINS;
    const int n   = t / NBINS;
    const int pw  = bin % P_OUT;
    const int ph  = bin / P_OUT;

    const float* roi = rois + n * 5;
    const int   b   = (int)roi[0];
    const float rsw = rintf(roi[1]) * SPATIAL_SCALE - 0.5f;
    const float rsh = rintf(roi[2]) * SPATIAL_SCALE - 0.5f;
    const float rew = (rintf(roi[3]) + 1.0f) * SPATIAL_SCALE - 0.5f;
    const float reh = (rintf(roi[4]) + 1.0f) * SPATIAL_SCALE - 0.5f;
    const float rw  = fmaxf(rew - rsw, 0.1f);
    const float rh  = fmaxf(reh - rsh, 0.1f);
    const float binw = rw * (1.0f / P_OUT);
    const float binh = rh * (1.0f / P_OUT);
    const float subw = binw * (1.0f / SAMPLE_PER_PART);
    const float subh = binh * (1.0f / SAMPLE_PER_PART);

    // part_h == ph, part_w == pw (P == PART_SIZE == 7, fp32-exact)
    const float tx = offset[(n * 2 + 0) * (PART_SIZE * PART_SIZE) + ph * PART_SIZE + pw] * TRANS_STD;
    const float ty = offset[(n * 2 + 1) * (PART_SIZE * PART_SIZE) + ph * PART_SIZE + pw] * TRANS_STD;

    const float wstart = (float)pw * binw + rsw + tx * rw;
    const float hstart = (float)ph * binh + rsh + ty * rh;

    BinParam p;
    // ---- x axis ----
    {
        const int F = (int)floorf(fminf(fmaxf(wstart, 0.0f), 127.0f));
        float cX = 0.0f;
        float W8[8] = {0,0,0,0,0,0,0,0};
        #pragma unroll
        for (int j = 0; j < SAMPLE_PER_PART; ++j) {
            const float w = wstart + (float)j * subw;
            const bool  v = (w >= -0.5f) && (w <= 127.5f);
            const float wc = fminf(fmaxf(w, 0.0f), 127.0f);
            const int f = (int)floorf(wc);
            const int c = (int)ceilf(wc);
            const float dx = wc - (float)f;
            if (v) {
                W8[min(max(f - F, 0), 7)] += 1.0f - dx;
                W8[min(max(c - F, 0), 7)] += dx;
                cX += 1.0f;
            }
        }
        const float wcL = fminf(fmaxf(wstart + 3.0f * subw, 0.0f), 127.0f);
        p.fx = F;
        p.nx = min((int)ceilf(wcL) - F + 1, 8);
        const float s = 1.0f / fmaxf(cX, 1.0f);
        #pragma unroll
        for (int k = 0; k < 8; ++k) p.wx[k] = W8[k] * s;
    }
    // ---- y axis ----
    {
        const int F = (int)floorf(fminf(fmaxf(hstart, 0.0f), 127.0f));
        float cY = 0.0f;
        float W8[8] = {0,0,0,0,0,0,0,0};
        #pragma unroll
        for (int j = 0; j < SAMPLE_PER_PART; ++j) {
            const float h = hstart + (float)j * subh;
            const bool  v = (h >= -0.5f) && (h <= 127.5f);
            const float hc = fminf(fmaxf(h, 0.0f), 127.0f);
            const int f = (int)floorf(hc);
            const int c = (int)ceilf(hc);
            const float dy = hc - (float)f;
            if (v) {
                W8[min(max(f - F, 0), 7)] += 1.0f - dy;
                W8[min(max(c - F, 0), 7)] += dy;
                cY += 1.0f;
            }
        }
        const float hcL = fminf(fmaxf(hstart + 3.0f * subh, 0.0f), 127.0f);
        p.fy = F;
        p.ny = min((int)ceilf(hcL) - F + 1, 8);
        const float s = 1.0f / fmaxf(cY, 1.0f);
        #pragma unroll
        for (int k = 0; k < 8; ++k) p.wy[k] = W8[k] * s;
    }
    p.b = b;
    p.pad[0] = p.pad[1] = p.pad[2] = 0;
    prm[t] = p;
}

// ---------------------------------------------------------------------------
// Kernel 2: gather (precomputed BinParam) + coalesced-run stores.
// Block = one 4-aligned bin group of one roi (wave w -> bin g*4+w).
// ---------------------------------------------------------------------------
__global__ __launch_bounds__(256) void gather_kernel(
    const __half* __restrict__ dataT,   // [B][H*W][C] f16
    const BinParam* __restrict__ prm,
    float* __restrict__ outp)           // [n][c][bin]
{
    __shared__ float lds[4 * 2 * 256];

    const int bid  = blockIdx.x;
    const int bswz = (bid & 7) * (GBLOCKS / 8) + (bid >> 3);   // bijective XCD swizzle
    const int w    = threadIdx.x >> 6;
    const int lane = threadIdx.x & 63;

    const int n   = bswz / GROUPS;
    const int g   = bswz - n * GROUPS;
    const int bin = g * 4 + w;               // >= 49 only when g == 12, w > 0

    if (bin < NBINS) {
        const BinParam p = prm[n * NBINS + bin];

        const int half_id = lane >> 5;           // 0: even x-pixels, 1: odd
        const int c0      = (lane & 31) * 8;     // 8 channels per lane

        float mwx[4];
        if (half_id) { mwx[0] = p.wx[1]; mwx[1] = p.wx[3]; mwx[2] = p.wx[5]; mwx[3] = p.wx[7]; }
        else         { mwx[0] = p.wx[0]; mwx[1] = p.wx[2]; mwx[2] = p.wx[4]; mwx[3] = p.wx[6]; }

        const __half* base = dataT
            + ((size_t)p.b * (128 * 128) + (size_t)p.fy * 128 + p.fx) * 256 + c0;

        float acc[8] = {0,0,0,0,0,0,0,0};

        #pragma unroll
        for (int ky = 0; ky < 8; ++ky) {
            if (ky >= p.ny) break;                              // wave-uniform
            const float wyk = p.wy[ky];                          // static index
            const __half* rowp = base + (size_t)ky * (128 * 256);
            #pragma unroll
            for (int kp = 0; kp < 4; ++kp) {
                if (2 * kp >= p.nx) break;                      // wave-uniform
                const int pxr = 2 * kp + half_id;
                const int px  = min(pxr, p.nx - 1);             // clamp addr; weight 0 there
                const float wgt = wyk * mwx[kp];
                const uint4 u = *(const uint4*)(rowp + (size_t)px * 256);
                {
                    __half2 h = *reinterpret_cast<const __half2*>(&u.x);
                    float2 f = __half22float2(h);
                    acc[0] += wgt * f.x; acc[1] += wgt * f.y;
                }
                {
                    __half2 h = *reinterpret_cast<const __half2*>(&u.y);
                    float2 f = __half22float2(h);
                    acc[2] += wgt * f.x; acc[3] += wgt * f.y;
                }
                {
                    __half2 h = *reinterpret_cast<const __half2*>(&u.z);
                    float2 f = __half22float2(h);
                    acc[4] += wgt * f.x; acc[5] += wgt * f.y;
                }
                {
                    __half2 h = *reinterpret_cast<const __half2*>(&u.w);
                    float2 f = __half22float2(h);
                    acc[6] += wgt * f.x; acc[7] += wgt * f.y;
                }
            }
        }

        // stage partials: lds[w][half][c]
        float* myl = &lds[(w * 2 + half_id) * 256 + c0];
        #pragma unroll
        for (int k = 0; k < 8; ++k) myl[k] = acc[k];
    }
    __syncthreads();

    // coalesced-run store: idx -> (c = idx>>2, j = idx&3); 4-bin runs per c.
    const int t = threadIdx.x;
    const size_t obase = (size_t)n * (OUTPUT_DIM * NBINS) + g * 4;
    #pragma unroll
    for (int it = 0; it < 4; ++it) {
        const int idx = it * 256 + t;
        const int c = idx >> 2;
        const int j = idx & 3;
        if (g * 4 + j < NBINS) {
            const float v = lds[(j * 2 + 0) * 256 + c] + lds[(j * 2 + 1) * 256 + c];
            outp[obase + (size_t)c * NBINS + j] = v;
        }
    }
}

// ---------------------------------------------------------------------------
// Fallback (round-0): direct gather from NCHW layout, used if ws too small.
// ---------------------------------------------------------------------------
__global__ __launch_bounds__(256) void dpsroi_kernel_direct(
    const float* __restrict__ data,
    const float* __restrict__ rois,
    const float* __restrict__ offset,
    float* __restrict__ out,
    int total)
{
    int idx = blockIdx.x * blockDim.x + threadIdx.x;
    if (idx >= total) return;

    const int P = P_OUT;
    const int C = OUTPUT_DIM;
    const int H = 128, W = 128;

    int pw = idx % P;
    int ph = (idx / P) % P;
    int c  = (idx / (P * P)) % C;
    int n  = idx / (P * P * C);

    const float* roi = rois + n * 5;
    int   b   = (int)roi[0];
    float rsw = rintf(roi[1]) * SPATIAL_SCALE - 0.5f;
    float rsh = rintf(roi[2]) * SPATIAL_SCALE - 0.5f;
    float rew = (rintf(roi[3]) + 1.0f) * SPATIAL_SCALE - 0.5f;
    float reh = (rintf(roi[4]) + 1.0f) * SPATIAL_SCALE - 0.5f;
    float rw  = fmaxf(rew - rsw, 0.1f);
    float rh  = fmaxf(reh - rsh, 0.1f);
    float binw = rw / P, binh = rh / P;
    float subw = binw / SAMPLE_PER_PART, subh = binh / SAMPLE_PER_PART;

    float tx = offset[(n * 2 + 0) * (PART_SIZE * PART_SIZE) + ph * PART_SIZE + pw] * TRANS_STD;
    float ty = offset[(n * 2 + 1) * (PART_SIZE * PART_SIZE) + ph * PART_SIZE + pw] * TRANS_STD;

    float wstart = (float)pw * binw + rsw + tx * rw;
    float hstart = (float)ph * binh + rsh + ty * rh;

    const float* dplane = data + (size_t)(b * C + c) * (H * W);

    float ssum = 0.0f, count = 0.0f;
    #pragma unroll
    for (int ihs = 0; ihs < SAMPLE_PER_PART; ++ihs) {
        float hh = hstart + (float)ihs * subh;
        #pragma unroll
        for (int iws = 0; iws < SAMPLE_PER_PART; ++iws) {
            float ww = wstart + (float)iws * subw;
            float valid = ((ww >= -0.5f) & (ww <= (float)W - 0.5f) &
                           (hh >= -0.5f) & (hh <= (float)H - 0.5f)) ? 1.0f : 0.0f;
            float wc = fminf(fmaxf(ww, 0.0f), (float)W - 1.0f);
            float hc = fminf(fmaxf(hh, 0.0f), (float)H - 1.0f);
            float y0f = floorf(hc), x0f = floorf(wc);
            float y1f = ceilf(hc),  x1f = ceilf(wc);
            float dy = hc - y0f, dx = wc - x0f;
            int y0 = (int)y0f, y1 = (int)y1f;
            int x0 = (int)x0f, x1 = (int)x1f;
            float v00 = dplane[y0 * W + x0];
            float v01 = dplane[y0 * W + x1];
            float v10 = dplane[y1 * W + x0];
            float v11 = dplane[y1 * W + x1];
            float val = (1.0f - dy) * (1.0f - dx) * v00
                      + (1.0f - dy) * dx          * v01
                      + dy          * (1.0f - dx) * v10
                      + dy          * dx          * v11;
            ssum  += val * valid;
            count += valid;
        }
    }
    out[idx] = (count > 0.0f) ? (ssum / fmaxf(count, 1.0f)) : 0.0f;
}

extern "C" void kernel_launch(void* const* d_in, const int* in_sizes, int n_in,
                              void* d_out, int out_size, void* d_ws, size_t ws_size,
                              hipStream_t stream) {
    const float* data   = (const float*)d_in[0];
    const float* rois   = (const float*)d_in[1];
    const float* offset = (const float*)d_in[2];
    float* out = (float*)d_out;

    const size_t szT = (size_t)2 * 16384 * 256 * sizeof(__half);   // 16.78 MB
    const size_t szP = (size_t)NWAVES * sizeof(BinParam);          //  0.60 MB

    if (ws_size >= szT + szP) {
        __half*   dataT = (__half*)d_ws;
        BinParam* prm   = (BinParam*)((char*)d_ws + szT);

        prep_kernel<<<TPBLOCKS + PRMBLOCKS, 256, 0, stream>>>(data, rois, offset, dataT, prm);
        gather_kernel<<<GBLOCKS, 256, 0, stream>>>(dataT, prm, out);
    } else {
        int total = out_size;
        dpsroi_kernel_direct<<<(total + 255) / 256, 256, 0, stream>>>(data, rois, offset, out, total);
    }
}